// Round 2
// baseline (146.061 us; speedup 1.0000x reference)
//
#include <hip/hip_runtime.h>

// Matcher: anchors [N=1024,2] fp32, gt_boxes [B=128,M=256,4] fp32.
// Both boxes are origin-centered, so:
//   iw = min(aw, gtw), ih = min(ah, gth)
//   iou = iw*ih / (aw*ah + gtw*gth - iw*ih)
// Outputs (concatenated float32): matches [B,M] (argmax over N, first-max
// semantics), then ious [B,N,M].
//
// v3: write-BW focus. Evidence so far: store LAYOUT is not the limiter
// (v1 half-rows vs v2 full rows: identical ~53 us kernel time, 2.5 TB/s).
// Remaining axes: (a) occupancy — fill kernel that hits 6.6 TB/s runs 32
// waves/CU, we ran 16; (b) L2 streaming — ious are written once, never
// re-read -> nontemporal stores. v3: 2048 blocks x 256 thr,
// __launch_bounds__(256,8) => <=64 VGPR => 8 blocks/CU = 32 waves/CU,
// nontemporal full-row float4 stores. Argmax goes through a 4 MB ws
// (16 n-slices) + tiny reduce kernel, all ascending-n + strict > to keep
// first-max semantics.

#define N_ANCH 1024
#define B_SZ   128
#define M_SZ   256
#define NS     16                // n-slices per b
#define NPB    (N_ANCH / NS)     // 64 n rows per block
#define NWAVES 4                 // 256 threads/block
#define NPW    (NPB / NWAVES)    // 16 n rows per wave

typedef float f4v __attribute__((ext_vector_type(4)));

__global__ __launch_bounds__(256, 8) void iou_kernel(
    const float* __restrict__ anchors,   // [N,2]
    const float* __restrict__ gt,        // [B,M,4]
    float* __restrict__ out,             // [B*M] matches ++ [B,N,M] ious
    float* __restrict__ ws_val,          // [B*NS, M] partial max
    int*   __restrict__ ws_idx)          // [B*NS, M] partial argmax
{
    __shared__ float2 s_anch[NPB];          // 512 B
    __shared__ float  s_val[NWAVES * M_SZ]; // 4 KB
    __shared__ int    s_idx[NWAVES * M_SZ]; // 4 KB

    const int tid  = threadIdx.x;
    const int lane = tid & 63;
    const int w    = tid >> 6;
    const int b    = blockIdx.x >> 4;
    const int s    = blockIdx.x & (NS - 1);

    // Stage this slice's 64 anchors (wave-uniform broadcast reads later).
    if (tid < NPB) s_anch[tid] = ((const float2*)anchors)[s * NPB + tid];

    // Per-lane gt boxes: 4 adjacent m (64 B contiguous per lane).
    const int m0 = lane * 4;
    const float4* g4 = (const float4*)gt + b * M_SZ + m0;
    float gtw[4], gth[4], areab[4];
    #pragma unroll
    for (int j = 0; j < 4; ++j) {
        float4 g = g4[j];
        gtw[j]   = g.z - g.x;
        gth[j]   = g.w - g.y;
        areab[j] = gtw[j] * gth[j];
    }

    __syncthreads();

    float bv[4] = {-1.f, -1.f, -1.f, -1.f};
    int   bi[4] = {0, 0, 0, 0};

    const int n_begin = s * NPB + w * NPW;
    float* __restrict__ row = out + (size_t)B_SZ * M_SZ
                            + (size_t)(b * N_ANCH + n_begin) * M_SZ + m0;
    const int a_base = w * NPW;

    // One IoU; J is a compile-time constant.
    #define IOU1(J, DST)                                                    \
    {                                                                       \
        float iw    = fminf(a.x, gtw[J]);                                   \
        float ih    = fminf(a.y, gth[J]);                                   \
        float inter = iw * ih;                                              \
        float iou   = __fdividef(inter, areaa + areab[J] - inter);          \
        DST = iou;                                                          \
        if (iou > bv[J]) { bv[J] = iou; bi[J] = n; }  /* strict >: first */ \
    }

    #pragma unroll 2
    for (int i = 0; i < NPW; ++i) {
        const int n = n_begin + i;
        float2 a = s_anch[a_base + i];      // wave-uniform -> LDS broadcast
        float areaa = a.x * a.y;
        f4v r;
        IOU1(0, r.x)
        IOU1(1, r.y)
        IOU1(2, r.z)
        IOU1(3, r.w)
        __builtin_nontemporal_store(r, (f4v*)row);  // streaming: never re-read
        row += M_SZ;                        // next n row (+1 KB, contiguous)
    }
    #undef IOU1

    // Per-wave partials -> LDS.
    #pragma unroll
    for (int j = 0; j < 4; ++j) {
        s_val[w * M_SZ + m0 + j] = bv[j];
        s_idx[w * M_SZ + m0 + j] = bi[j];
    }
    __syncthreads();

    // Reduce 4 wave-partials per m (blockDim == M_SZ: one thread per m).
    // Waves are in ascending-n order; strict > keeps first-occurrence.
    {
        float v  = s_val[tid];
        int   ix = s_idx[tid];
        #pragma unroll
        for (int ww = 1; ww < NWAVES; ++ww) {
            float v2 = s_val[ww * M_SZ + tid];
            if (v2 > v) { v = v2; ix = s_idx[ww * M_SZ + tid]; }
        }
        ws_val[(b * NS + s) * M_SZ + tid] = v;
        ws_idx[(b * NS + s) * M_SZ + tid] = ix;
    }
}

// Combine the NS per-slice partials (ascending s + strict > = first max).
__global__ __launch_bounds__(256) void match_kernel(
    const float* __restrict__ ws_val,
    const int*   __restrict__ ws_idx,
    float* __restrict__ out)
{
    const int t = blockIdx.x * 256 + threadIdx.x;   // 0 .. B*M-1
    const int b = t >> 8;            // M_SZ == 256
    const int m = t & (M_SZ - 1);
    const int base = b * NS * M_SZ + m;
    float v  = ws_val[base];
    int   ix = ws_idx[base];
    #pragma unroll
    for (int q = 1; q < NS; ++q) {
        float v2 = ws_val[base + q * M_SZ];
        if (v2 > v) { v = v2; ix = ws_idx[base + q * M_SZ]; }
    }
    out[t] = (float)ix;
}

extern "C" void kernel_launch(void* const* d_in, const int* in_sizes, int n_in,
                              void* d_out, int out_size, void* d_ws, size_t ws_size,
                              hipStream_t stream) {
    const float* anchors = (const float*)d_in[0];   // [1024,2]
    const float* gt      = (const float*)d_in[1];   // [128,256,4]
    float* out = (float*)d_out;

    float* ws_val = (float*)d_ws;
    int*   ws_idx = (int*)((char*)d_ws
                   + (size_t)B_SZ * NS * M_SZ * sizeof(float));

    iou_kernel<<<dim3(B_SZ * NS), dim3(256), 0, stream>>>(
        anchors, gt, out, ws_val, ws_idx);
    match_kernel<<<dim3(B_SZ * M_SZ / 256), dim3(256), 0, stream>>>(
        ws_val, ws_idx, out);
}

// Round 3
// 138.458 us; speedup vs baseline: 1.0549x; 1.0549x over previous
//
#include <hip/hip_runtime.h>

// Matcher: anchors [N=1024,2] fp32, gt_boxes [B=128,M=256,4] fp32.
// Both boxes are origin-centered, so:
//   iw = min(aw, gtw), ih = min(ah, gth)
//   iou = iw*ih / (aw*ah + gtw*gth - iw*ih)
// Outputs (concatenated float32): matches [B,M] (argmax over N, first-max
// semantics), then ious [B,N,M].
//
// FINAL (v2 revert): write-BW-roofline kernel. Measured decomposition of the
// bench window: poison fill ~82-85 us (537 MB @ 6.3 TB/s = HBM ceiling,
// harness-fixed) + ~20 tiny reset dispatches ~30-35 us (harness-fixed) +
// iou_kernel ~21-24 us (134 MB output / 6.3 TB/s = write roofline) +
// match_kernel ~3 us. Evidence: three structurally different variants
// (8B/lane strided @16 waves/CU, 16B/lane rows @16 waves/CU, full-occupancy
// + nontemporal) all within +-4% -> kernel share is at the write floor;
// NT stores regressed ~4 us (cached stores let dirty L2 lines drain during
// subsequent harness dispatches, outside our window). Keep cached stores.

#define N_ANCH 1024
#define B_SZ   128
#define M_SZ   256
#define NQ     4                 // n-quarters per b
#define NPB    (N_ANCH / NQ)     // 256 n rows per block
#define NWAVES 8
#define NPW    (NPB / NWAVES)    // 32 n rows per wave

__global__ __launch_bounds__(512) void iou_kernel(
    const float* __restrict__ anchors,   // [N,2]
    const float* __restrict__ gt,        // [B,M,4]
    float* __restrict__ out,             // [B*M] matches ++ [B,N,M] ious
    float* __restrict__ ws_val,          // [B*NQ, M] partial max
    int*   __restrict__ ws_idx)          // [B*NQ, M] partial argmax
{
    __shared__ float2 s_anch[NPB];          // 2 KB
    __shared__ float  s_val[NWAVES * M_SZ]; // 8 KB
    __shared__ int    s_idx[NWAVES * M_SZ]; // 8 KB

    const int tid  = threadIdx.x;
    const int lane = tid & 63;
    const int w    = tid >> 6;
    const int b    = blockIdx.x >> 2;
    const int q    = blockIdx.x & 3;

    // Stage this block's 256 anchors (wave-uniform broadcast reads later).
    if (tid < NPB) s_anch[tid] = ((const float2*)anchors)[q * NPB + tid];

    // Per-lane gt boxes: 4 adjacent m (64 B contiguous per lane).
    const int m0 = lane * 4;
    const float4* g4 = (const float4*)gt + b * M_SZ + m0;
    float gtw[4], gth[4], areab[4];
    #pragma unroll
    for (int j = 0; j < 4; ++j) {
        float4 g = g4[j];
        gtw[j]   = g.z - g.x;
        gth[j]   = g.w - g.y;
        areab[j] = gtw[j] * gth[j];
    }

    __syncthreads();

    float bv[4] = {-1.f, -1.f, -1.f, -1.f};
    int   bi[4] = {0, 0, 0, 0};

    const int n_begin = q * NPB + w * NPW;
    float* __restrict__ row = out + (size_t)B_SZ * M_SZ
                            + (size_t)(b * N_ANCH + n_begin) * M_SZ + m0;
    const int a_base = w * NPW;

    // One IoU; J is a compile-time constant, DST an l-value in float4 r.
    #define IOU1(J, DST)                                                    \
    {                                                                       \
        float iw    = fminf(a.x, gtw[J]);                                   \
        float ih    = fminf(a.y, gth[J]);                                   \
        float inter = iw * ih;                                              \
        float iou   = __fdividef(inter, areaa + areab[J] - inter);          \
        DST = iou;                                                          \
        if (iou > bv[J]) { bv[J] = iou; bi[J] = n; }  /* strict >: first */ \
    }

    #pragma unroll 4
    for (int i = 0; i < NPW; ++i) {
        const int n = n_begin + i;
        float2 a = s_anch[a_base + i];      // wave-uniform -> LDS broadcast
        float areaa = a.x * a.y;
        float4 r;
        IOU1(0, r.x)
        IOU1(1, r.y)
        IOU1(2, r.z)
        IOU1(3, r.w)
        *(float4*)row = r;                  // full-row 16 B/lane cached store
        row += M_SZ;                        // next n row (+1 KB, contiguous)
    }
    #undef IOU1

    // Per-wave partials -> LDS.
    #pragma unroll
    for (int j = 0; j < 4; ++j) {
        s_val[w * M_SZ + m0 + j] = bv[j];
        s_idx[w * M_SZ + m0 + j] = bi[j];
    }
    __syncthreads();

    // Reduce 8 wave-partials per m. Waves are in ascending-n order; strict >
    // preserves argmax first-occurrence semantics.
    if (tid < M_SZ) {
        float v  = s_val[tid];
        int   ix = s_idx[tid];
        #pragma unroll
        for (int ww = 1; ww < NWAVES; ++ww) {
            float v2 = s_val[ww * M_SZ + tid];
            if (v2 > v) { v = v2; ix = s_idx[ww * M_SZ + tid]; }
        }
        ws_val[(b * NQ + q) * M_SZ + tid] = v;
        ws_idx[(b * NQ + q) * M_SZ + tid] = ix;
    }
}

// Combine the NQ per-quarter partials (ascending q + strict > = first max).
__global__ __launch_bounds__(512) void match_kernel(
    const float* __restrict__ ws_val,
    const int*   __restrict__ ws_idx,
    float* __restrict__ out)
{
    const int t = blockIdx.x * 512 + threadIdx.x;   // 0 .. B*M-1
    const int b = t >> 8;            // M_SZ == 256
    const int m = t & (M_SZ - 1);
    const int base = b * NQ * M_SZ + m;
    float v  = ws_val[base];
    int   ix = ws_idx[base];
    #pragma unroll
    for (int q = 1; q < NQ; ++q) {
        float v2 = ws_val[base + q * M_SZ];
        if (v2 > v) { v = v2; ix = ws_idx[base + q * M_SZ]; }
    }
    out[t] = (float)ix;
}

extern "C" void kernel_launch(void* const* d_in, const int* in_sizes, int n_in,
                              void* d_out, int out_size, void* d_ws, size_t ws_size,
                              hipStream_t stream) {
    const float* anchors = (const float*)d_in[0];   // [1024,2]
    const float* gt      = (const float*)d_in[1];   // [128,256,4]
    float* out = (float*)d_out;

    float* ws_val = (float*)d_ws;
    int*   ws_idx = (int*)((char*)d_ws
                   + (size_t)B_SZ * NQ * M_SZ * sizeof(float));

    iou_kernel<<<dim3(B_SZ * NQ), dim3(512), 0, stream>>>(
        anchors, gt, out, ws_val, ws_idx);
    match_kernel<<<dim3(B_SZ * M_SZ / 512), dim3(512), 0, stream>>>(
        ws_val, ws_idx, out);
}